// Round 15
// baseline (238.602 us; speedup 1.0000x reference)
//
#include <hip/hip_runtime.h>
#include <hip/hip_bf16.h>
#include <cstdint>
#include <cstddef>

#define N_NODES 20000
#define N_EDGES 320000
#define N_GRAPHS 512
#define IN_FEATS 128
#define HID 256

typedef __bf16 bhalf;
typedef __bf16 bhalf8 __attribute__((ext_vector_type(8)));
typedef __bf16 bhalf4 __attribute__((ext_vector_type(4)));
typedef __bf16 bhalf2 __attribute__((ext_vector_type(2)));
typedef float f32x4 __attribute__((ext_vector_type(4)));

// Bijective XCD-aware block swizzle (m204).
__device__ __forceinline__ int2 xcd_swz(int bx, int by, int nbx, int nby)
{
    int lid = by * nbx + bx;
    int nwg = nbx * nby;
    int q = nwg >> 3, r = nwg & 7;
    int xcd = lid & 7, loc = lid >> 3;
    int s = (xcd < r ? xcd * (q + 1) : r * (q + 1) + (xcd - r) * q) + loc;
    return make_int2(s % nbx, s / nbx);
}

// ---------------------------------------------------------------------------
// bf16 MFMA GEMM (head layers): C = A @ Bt^T. 64x64 tile, BK=64, 4 waves.
// Split-K via gridDim.z (fp32 partials). XCD-swizzled.
// CIN>0: A operand is CIN fp32 split-K partial planes of the PREVIOUS GEMM
// ([z][M][K], z-stride M*K); staging sums them + biasA + relu -> bf16 inline
// (fuses the previous splitk_combine away).
// ---------------------------------------------------------------------------
template<int RELU, int OUTBF16, int CIN>
__global__ __launch_bounds__(256) void gemm_mfma(const void* __restrict__ Av,
                                                 const bhalf* __restrict__ Bt,
                                                 void* __restrict__ Cv,
                                                 const float* __restrict__ bias,
                                                 const float* __restrict__ biasA,
                                                 int M, int K, int ldc)
{
    __shared__ bhalf As[64 * 64];
    __shared__ bhalf Bs[64 * 64];

    const int t = threadIdx.x;
    const int lane = t & 63, wid = t >> 6;
    const int wm0 = (wid >> 1) * 32, wn0 = (wid & 1) * 32;
    int2 bsw = xcd_swz(blockIdx.x, blockIdx.y, gridDim.x, gridDim.y);
    const int m0 = bsw.y * 64, n0 = bsw.x * 64;
    const int S = gridDim.z, kz = blockIdx.z;
    const int Ks = K / S;

    const int srow = t >> 2;
    const int sc0 = (t & 3) << 3;

    f32x4 acc[2][2] = {};
    uint4 ra0, ra1, rb0, rb1;

    const int grow = m0 + srow;
    const bool mok = grow < M;
    const bhalf* Abase = (const bhalf*)Av + (size_t)grow * K + (size_t)kz * Ks;
    const float* Afb   = (const float*)Av + (size_t)grow * K + (size_t)kz * Ks;
    const size_t zstr = (size_t)M * K;
    const bhalf* Bbase = Bt + (size_t)(n0 + srow) * K + (size_t)kz * Ks;

    if (CIN == 0) {
        ra0 = mok ? *(const uint4*)(Abase + sc0)      : make_uint4(0u,0u,0u,0u);
        ra1 = mok ? *(const uint4*)(Abase + sc0 + 32) : make_uint4(0u,0u,0u,0u);
    }
    rb0 = *(const uint4*)(Bbase + sc0);
    rb1 = *(const uint4*)(Bbase + sc0 + 32);

    const int swz = (srow & 7) << 3;
    for (int k0 = 0; k0 < Ks; k0 += 64) {
        __syncthreads();
        if (CIN == 0) {
            *(uint4*)&As[srow * 64 + (sc0 ^ swz)]        = ra0;
            *(uint4*)&As[srow * 64 + ((sc0 + 32) ^ swz)] = ra1;
        } else {
            // combine-in staging: sum CIN partial planes + biasA + relu -> bf16
            int kg = kz * Ks + k0;               // global A column base
            float a0[8], a1[8];
#pragma unroll
            for (int j = 0; j < 8; ++j) {
                a0[j] = biasA[kg + sc0 + j];
                a1[j] = biasA[kg + sc0 + 32 + j];
            }
            if (mok) {
#pragma unroll
                for (int z = 0; z < CIN; ++z) {
                    const float* p = Afb + (size_t)z * zstr + k0;
                    float4 q0 = *(const float4*)(p + sc0);
                    float4 q1 = *(const float4*)(p + sc0 + 4);
                    float4 q2 = *(const float4*)(p + sc0 + 32);
                    float4 q3 = *(const float4*)(p + sc0 + 36);
                    a0[0] += q0.x; a0[1] += q0.y; a0[2] += q0.z; a0[3] += q0.w;
                    a0[4] += q1.x; a0[5] += q1.y; a0[6] += q1.z; a0[7] += q1.w;
                    a1[0] += q2.x; a1[1] += q2.y; a1[2] += q2.z; a1[3] += q2.w;
                    a1[4] += q3.x; a1[5] += q3.y; a1[6] += q3.z; a1[7] += q3.w;
                }
            }
            bhalf8 o0, o1;
#pragma unroll
            for (int j = 0; j < 8; ++j) {
                o0[j] = (bhalf)(mok ? fmaxf(a0[j], 0.f) : 0.f);
                o1[j] = (bhalf)(mok ? fmaxf(a1[j], 0.f) : 0.f);
            }
            *(bhalf8*)&As[srow * 64 + (sc0 ^ swz)]        = o0;
            *(bhalf8*)&As[srow * 64 + ((sc0 + 32) ^ swz)] = o1;
        }
        *(uint4*)&Bs[srow * 64 + (sc0 ^ swz)]        = rb0;
        *(uint4*)&Bs[srow * 64 + ((sc0 + 32) ^ swz)] = rb1;
        __syncthreads();
        if (k0 + 64 < Ks) {
            if (CIN == 0) {
                const bhalf* An = Abase + k0 + 64;
                ra0 = mok ? *(const uint4*)(An + sc0)      : make_uint4(0u,0u,0u,0u);
                ra1 = mok ? *(const uint4*)(An + sc0 + 32) : make_uint4(0u,0u,0u,0u);
            }
            const bhalf* Bn = Bbase + k0 + 64;
            rb0 = *(const uint4*)(Bn + sc0);
            rb1 = *(const uint4*)(Bn + sc0 + 32);
        }
#pragma unroll
        for (int kb = 0; kb < 2; ++kb) {
            const int kc = kb * 32 + (lane >> 4) * 8;
            bhalf8 af[2], bfr[2];
#pragma unroll
            for (int i = 0; i < 2; ++i) {
                int rA = wm0 + i * 16 + (lane & 15);
                af[i] = *(const bhalf8*)&As[rA * 64 + (kc ^ ((rA & 7) << 3))];
                int rB = wn0 + i * 16 + (lane & 15);
                bfr[i] = *(const bhalf8*)&Bs[rB * 64 + (kc ^ ((rB & 7) << 3))];
            }
#pragma unroll
            for (int mi = 0; mi < 2; ++mi)
#pragma unroll
                for (int ni = 0; ni < 2; ++ni)
                    acc[mi][ni] = __builtin_amdgcn_mfma_f32_16x16x32_bf16(
                        af[mi], bfr[ni], acc[mi][ni], 0, 0, 0);
        }
    }

#pragma unroll
    for (int mi = 0; mi < 2; ++mi)
#pragma unroll
        for (int ni = 0; ni < 2; ++ni) {
            int col = n0 + wn0 + ni * 16 + (lane & 15);
            f32x4 v = acc[mi][ni];
            if (S > 1) {
#pragma unroll
                for (int r = 0; r < 4; ++r) {
                    int row = m0 + wm0 + mi * 16 + (lane >> 4) * 4 + r;
                    if (row < M)
                        ((float*)Cv)[((size_t)kz * M + row) * ldc + col] = v[r];
                }
            } else {
                float bb = bias ? bias[col] : 0.f;
#pragma unroll
                for (int r = 0; r < 4; ++r) {
                    int row = m0 + wm0 + mi * 16 + (lane >> 4) * 4 + r;
                    if (row < M) {
                        float x = v[r] + bb;
                        if (RELU) x = fmaxf(x, 0.f);
                        if (OUTBF16) ((bhalf*)Cv)[(size_t)row * ldc + col] = (bhalf)x;
                        else         ((float*)Cv)[(size_t)row * ldc + col] = x;
                    }
                }
            }
        }
}

// ---------------------------------------------------------------------------
// Fused GCN layer GEMM, two-phase (m then r). BN=1: BN1 affine applied to the
// Ax tile during LDS staging. vout must NOT alias Aagg/Ax (round-13 lesson).
// ---------------------------------------------------------------------------
template<int BN>
__global__ __launch_bounds__(256) void gcn_gemm_fused(const bhalf* __restrict__ Aagg,
                                                      const bhalf* __restrict__ Ax,
                                                      const bhalf* __restrict__ BW,
                                                      const bhalf* __restrict__ BrW,
                                                      const float* __restrict__ b,
                                                      const float* __restrict__ rb,
                                                      bhalf* __restrict__ vout,
                                                      float* __restrict__ stats,
                                                      int M, int K,
                                                      const float* __restrict__ bnstats,
                                                      const float* __restrict__ bng,
                                                      const float* __restrict__ bnbe,
                                                      float inv_n)
{
    __shared__ bhalf As[64 * 64];
    __shared__ bhalf Bs[64 * 64];
    __shared__ float ssum[64], ssq[64];
    __shared__ float bnS[256], bnB[256];

    const int t = threadIdx.x;
    const int lane = t & 63, wid = t >> 6;
    const int wm0 = (wid >> 1) * 32, wn0 = (wid & 1) * 32;
    int2 bsw = xcd_swz(blockIdx.x, blockIdx.y, gridDim.x, gridDim.y);
    const int m0 = bsw.y * 64, n0 = bsw.x * 64;

    const int srow = t >> 2;
    const int sc0 = (t & 3) << 3;
    const int nk = K >> 6;

    if (BN && t < K) {
        float mu = bnstats[t] * inv_n;
        float rs = rsqrtf(bnstats[K + t] * inv_n - mu * mu + 1e-5f);
        float s = bng[t] * rs;
        bnS[t] = s;
        bnB[t] = bnbe[t] - mu * s;
    }

    f32x4 accM[2][2] = {};
    f32x4 accR[2][2] = {};
    uint4 ra0, ra1, rb0, rb1;

    const bool mok = (m0 + srow) < M;
    const bhalf* A0r = Aagg + (size_t)(m0 + srow) * K;
    const bhalf* A1r = Ax + (size_t)(m0 + srow) * K;
    const bhalf* B0r = BW + (size_t)(n0 + srow) * K;
    const bhalf* B1r = BrW + (size_t)(n0 + srow) * K;

    ra0 = mok ? *(const uint4*)(A0r + sc0)      : make_uint4(0u,0u,0u,0u);
    ra1 = mok ? *(const uint4*)(A0r + sc0 + 32) : make_uint4(0u,0u,0u,0u);
    rb0 = *(const uint4*)(B0r + sc0);
    rb1 = *(const uint4*)(B0r + sc0 + 32);

    const int swz = (srow & 7) << 3;
    const int total = 2 * nk;
    if (BN) __syncthreads();
    for (int ii = 0; ii < total; ++ii) {
        __syncthreads();
        if (BN && ii >= nk) {
            int kb0 = ((ii - nk) << 6) + sc0;
            bhalf8 a0 = *(bhalf8*)&ra0, a1 = *(bhalf8*)&ra1;
#pragma unroll
            for (int j = 0; j < 8; ++j) {
                a0[j] = (bhalf)((float)a0[j] * bnS[kb0 + j] + bnB[kb0 + j]);
                a1[j] = (bhalf)((float)a1[j] * bnS[kb0 + 32 + j] + bnB[kb0 + 32 + j]);
            }
            ra0 = *(uint4*)&a0; ra1 = *(uint4*)&a1;
        }
        *(uint4*)&As[srow * 64 + (sc0 ^ swz)]        = ra0;
        *(uint4*)&As[srow * 64 + ((sc0 + 32) ^ swz)] = ra1;
        *(uint4*)&Bs[srow * 64 + (sc0 ^ swz)]        = rb0;
        *(uint4*)&Bs[srow * 64 + ((sc0 + 32) ^ swz)] = rb1;
        __syncthreads();
        int jj = ii + 1;
        if (jj < total) {
            bool seln = jj >= nk;
            int kk = (seln ? jj - nk : jj) << 6;
            const bhalf* Ab = (seln ? A1r : A0r) + kk;
            const bhalf* Bb = (seln ? B1r : B0r) + kk;
            ra0 = mok ? *(const uint4*)(Ab + sc0)      : make_uint4(0u,0u,0u,0u);
            ra1 = mok ? *(const uint4*)(Ab + sc0 + 32) : make_uint4(0u,0u,0u,0u);
            rb0 = *(const uint4*)(Bb + sc0);
            rb1 = *(const uint4*)(Bb + sc0 + 32);
        }
        const bool selc = ii >= nk;
#pragma unroll
        for (int kb = 0; kb < 2; ++kb) {
            const int kc = kb * 32 + (lane >> 4) * 8;
            bhalf8 af[2], bfr[2];
#pragma unroll
            for (int i = 0; i < 2; ++i) {
                int rA = wm0 + i * 16 + (lane & 15);
                af[i] = *(const bhalf8*)&As[rA * 64 + (kc ^ ((rA & 7) << 3))];
                int rB = wn0 + i * 16 + (lane & 15);
                bfr[i] = *(const bhalf8*)&Bs[rB * 64 + (kc ^ ((rB & 7) << 3))];
            }
            if (!selc) {
#pragma unroll
                for (int mi = 0; mi < 2; ++mi)
#pragma unroll
                    for (int ni = 0; ni < 2; ++ni)
                        accM[mi][ni] = __builtin_amdgcn_mfma_f32_16x16x32_bf16(
                            af[mi], bfr[ni], accM[mi][ni], 0, 0, 0);
            } else {
#pragma unroll
                for (int mi = 0; mi < 2; ++mi)
#pragma unroll
                    for (int ni = 0; ni < 2; ++ni)
                        accR[mi][ni] = __builtin_amdgcn_mfma_f32_16x16x32_bf16(
                            af[mi], bfr[ni], accR[mi][ni], 0, 0, 0);
            }
        }
    }

    if (t < 64) { ssum[t] = 0.f; ssq[t] = 0.f; }
    __syncthreads();
    float sloc[2] = {0.f, 0.f}, s2loc[2] = {0.f, 0.f};
#pragma unroll
    for (int ni = 0; ni < 2; ++ni) {
        int cl = wn0 + ni * 16 + (lane & 15);
        int c = n0 + cl;
        float bb = b[c], rbb = rb[c];
#pragma unroll
        for (int mi = 0; mi < 2; ++mi) {
            f32x4 a0v = accM[mi][ni], a1v = accR[mi][ni];
#pragma unroll
            for (int r = 0; r < 4; ++r) {
                int row = m0 + wm0 + mi * 16 + (lane >> 4) * 4 + r;
                if (row < M) {
                    float x = fmaxf(a0v[r] + bb, 0.f) + fmaxf(a1v[r] + rbb, 0.f);
                    vout[(size_t)row * HID + c] = (bhalf)x;
                    sloc[ni] += x;
                    s2loc[ni] += x * x;
                }
            }
        }
        atomicAdd(&ssum[cl], sloc[ni]);
        atomicAdd(&ssq[cl], s2loc[ni]);
    }
    __syncthreads();
    if (t < 64) {
        atomicAdd(&stats[n0 + t], ssum[t]);
        atomicAdd(&stats[HID + n0 + t], ssq[t]);
    }
}

// sum S split-K partials + bias + act (used once: rk2 -> zb)
template<int RELU, int OUTBF16>
__global__ __launch_bounds__(256) void splitk_combine(const float* __restrict__ part,
                                                      int S, int M, int N, int ldo,
                                                      const float* __restrict__ bias,
                                                      void* __restrict__ outv)
{
    int i = blockIdx.x * blockDim.x + threadIdx.x;
    int n4 = N >> 2;
    if (i >= M * n4) return;
    int row = i / n4, c4 = (i - row * n4) << 2;
    float4 s = make_float4(0.f, 0.f, 0.f, 0.f);
    for (int z = 0; z < S; ++z) {
        float4 p = *(const float4*)(part + ((size_t)z * M + row) * N + c4);
        s.x += p.x; s.y += p.y; s.z += p.z; s.w += p.w;
    }
    float4 bb = *(const float4*)(bias + c4);
    s.x += bb.x; s.y += bb.y; s.z += bb.z; s.w += bb.w;
    if (RELU) {
        s.x = fmaxf(s.x, 0.f); s.y = fmaxf(s.y, 0.f);
        s.z = fmaxf(s.z, 0.f); s.w = fmaxf(s.w, 0.f);
    }
    if (OUTBF16) {
        bhalf4 o = {(bhalf)s.x, (bhalf)s.y, (bhalf)s.z, (bhalf)s.w};
        *(bhalf4*)((bhalf*)outv + (size_t)row * ldo + c4) = o;
    } else {
        *(float4*)((float*)outv + (size_t)row * ldo + c4) = s;
    }
}

// last head layer: combine S partials + bias + relu, dot with W3
__global__ __launch_bounds__(128) void splitk_combine_dot(const float* __restrict__ part,
                                                          int S, int M, int N,
                                                          const float* __restrict__ bias,
                                                          const float* __restrict__ W3,
                                                          const float* __restrict__ b3,
                                                          float* __restrict__ out)
{
    int row = blockIdx.x, t = threadIdx.x;
    int c4 = t << 2;
    float4 s = make_float4(0.f, 0.f, 0.f, 0.f);
    for (int z = 0; z < S; ++z) {
        float4 p = *(const float4*)(part + ((size_t)z * M + row) * N + c4);
        s.x += p.x; s.y += p.y; s.z += p.z; s.w += p.w;
    }
    float4 bb = *(const float4*)(bias + c4);
    float4 w = *(const float4*)(W3 + c4);
    float d = fmaxf(s.x + bb.x, 0.f) * w.x + fmaxf(s.y + bb.y, 0.f) * w.y
            + fmaxf(s.z + bb.z, 0.f) * w.z + fmaxf(s.w + bb.w, 0.f) * w.w;
#pragma unroll
    for (int off = 32; off > 0; off >>= 1) d += __shfl_xor(d, off);
    __shared__ float ws2[2];
    if ((t & 63) == 0) ws2[t >> 6] = d;
    __syncthreads();
    if (t == 0) out[row] = ws2[0] + ws2[1] + b3[0];
}

// ---------------------------------------------------------------------------
// Prep mega-kernel: weight transpose+convert | input conversion | zeroing.
// ---------------------------------------------------------------------------
struct WEnt { const float* src; bhalf* dst; int K; int N; int tiles_end; };
struct PrepTab {
    WEnt e[8];
    const float* ca; bhalf* coa; int n4a;
    const float* cb; bhalf* cob; int n4b;
    uint4* zbase; int zn;
};

#define WTILES 4288
#define CONVB  3524

__global__ __launch_bounds__(256) void prep_batch(PrepTab tab)
{
    __shared__ float tile[32][33];
    int tb = blockIdx.x;
    int t = threadIdx.x;
    if (tb < WTILES) {
        int idx = 0;
#pragma unroll
        for (int i = 0; i < 8; ++i)
            if (tb >= tab.e[i].tiles_end) idx = i + 1;
        const WEnt& E = tab.e[idx];
        int t0 = idx ? tab.e[idx - 1].tiles_end : 0;
        int lt = tb - t0;
        int tX = E.N >> 5;
        int bx = (lt % tX) << 5;
        int by = (lt / tX) << 5;
        int tx = t & 31, ty = t >> 5;
#pragma unroll
        for (int i = 0; i < 32; i += 8)
            tile[ty + i][tx] = E.src[(size_t)(by + ty + i) * E.N + bx + tx];
        __syncthreads();
#pragma unroll
        for (int i = 0; i < 32; i += 8)
            E.dst[(size_t)(bx + ty + i) * E.K + by + tx] = (bhalf)tile[tx][ty + i];
    } else if (tb < WTILES + CONVB) {
        int i = (tb - WTILES) * 256 + t;
        const float* s; bhalf* d; int j;
        if (i < tab.n4a) { s = tab.ca; d = tab.coa; j = i; }
        else { j = i - tab.n4a; if (j >= tab.n4b) return; s = tab.cb; d = tab.cob; }
        float4 v = ((const float4*)s)[j];
        bhalf4 o = {(bhalf)v.x, (bhalf)v.y, (bhalf)v.z, (bhalf)v.w};
        ((bhalf4*)d)[j] = o;
    } else {
        int j = (tb - WTILES - CONVB) * 256 + t;
        if (j < tab.zn) tab.zbase[j] = make_uint4(0u, 0u, 0u, 0u);
    }
}

// ---------------------------------------------------------------------------
// CSR build
// ---------------------------------------------------------------------------
__global__ void csr_count(const int* __restrict__ dst, int* __restrict__ counts)
{
    int e = blockIdx.x * blockDim.x + threadIdx.x;
    if (e >= N_EDGES) return;
    atomicAdd(&counts[dst[e]], 1);
}

__global__ __launch_bounds__(256) void csr_scan_a(const int* __restrict__ counts,
                                                  int* __restrict__ bsum)
{
    int i = blockIdx.x * 256 + threadIdx.x;
    int v = (i < N_NODES) ? counts[i] : 0;
#pragma unroll
    for (int off = 32; off > 0; off >>= 1) v += __shfl_down(v, off);
    __shared__ int ws[4];
    if ((threadIdx.x & 63) == 0) ws[threadIdx.x >> 6] = v;
    __syncthreads();
    if (threadIdx.x == 0) bsum[blockIdx.x] = ws[0] + ws[1] + ws[2] + ws[3];
}

__global__ __launch_bounds__(256) void csr_scan_c(const int* __restrict__ counts,
                                                  const int* __restrict__ bsum, int nb,
                                                  int* __restrict__ offsets)
{
    int t = threadIdx.x, b = blockIdx.x;
    int i = b * 256 + t;
    int v = (i < N_NODES) ? counts[i] : 0;
    int x = v;
#pragma unroll
    for (int off = 1; off < 64; off <<= 1) {
        int y = __shfl_up(x, off);
        if ((t & 63) >= off) x += y;
    }
    __shared__ int wsum[4];
    __shared__ int tmp[128];
    __shared__ int addsh;
    if ((t & 63) == 63) wsum[t >> 6] = x;
    if (t < 128) tmp[t] = (t < nb) ? bsum[t] : 0;
    __syncthreads();
    if (t == 0) {
        int a = 0;
        for (int j = 0; j < b; ++j) a += tmp[j];
        addsh = a;
    }
    __syncthreads();
    int add = addsh;
    for (int w = 0; w < (t >> 6); ++w) add += wsum[w];
    int excl = x - v + add;
    if (i < N_NODES) offsets[i] = excl;
    if (i == N_NODES - 1) offsets[N_NODES] = excl + v;
}

__global__ void csr_fill(const int* __restrict__ src, const int* __restrict__ dst,
                         const int* __restrict__ offsets, int* __restrict__ cursor,
                         int* __restrict__ eidx)
{
    int e = blockIdx.x * blockDim.x + threadIdx.x;
    if (e >= N_EDGES) return;
    int d = dst[e];
    int slot = offsets[d] + atomicAdd(&cursor[d], 1);
    eidx[slot] = src[e];
}

__global__ void csr_sort_wave(const int* __restrict__ offsets, int* __restrict__ eidx)
{
    int gidx = blockIdx.x * blockDim.x + threadIdx.x;
    int n = gidx >> 6, lane = gidx & 63;
    if (n >= N_NODES) return;
    int lo = offsets[n], hi = offsets[n + 1];
    int cnt = hi - lo;
    if (cnt <= 1) return;
    if (cnt <= 64) {
        int v = (lane < cnt) ? eidx[lo + lane] : 0x7fffffff;
        int rank = 0;
        for (int j = 0; j < cnt; ++j) {
            int vj = __shfl(v, j);
            if (vj < v || (vj == v && j < lane)) ++rank;
        }
        if (lane < cnt) eidx[lo + rank] = v;
    } else if (lane == 0) {
        for (int i = lo + 1; i < hi; ++i) {
            int v = eidx[i]; int j = i - 1;
            while (j >= lo && eidx[j] > v) { eidx[j + 1] = eidx[j]; --j; }
            eidx[j + 1] = v;
        }
    }
}

// ---------------------------------------------------------------------------
// Gather-aggregate, layer 1 (128 cols): one wave = 4 edges/step, 16 lanes x
// 16B per row, shfl-xor combine across lane-groups.
// ---------------------------------------------------------------------------
__global__ __launch_bounds__(256) void edge_gather1(const bhalf* __restrict__ m,
                                                    const int* __restrict__ offsets,
                                                    const int* __restrict__ eidx,
                                                    bhalf* __restrict__ agg)
{
    int gidx = blockIdx.x * blockDim.x + threadIdx.x;
    int n = gidx >> 6, lane = gidx & 63;
    if (n >= N_NODES) return;
    int lo = offsets[n], hi = offsets[n + 1];
    int sub = lane >> 4;
    int colb = (lane & 15) * 8;
    float acc[8] = {};
    int i = lo;
    for (; i + 8 <= hi; i += 8) {
        bhalf8 v0 = *(const bhalf8*)(m + (size_t)eidx[i + sub] * IN_FEATS + colb);
        bhalf8 v1 = *(const bhalf8*)(m + (size_t)eidx[i + 4 + sub] * IN_FEATS + colb);
#pragma unroll
        for (int j = 0; j < 8; ++j) acc[j] += (float)v0[j] + (float)v1[j];
    }
    if (i + 4 <= hi) {
        bhalf8 v0 = *(const bhalf8*)(m + (size_t)eidx[i + sub] * IN_FEATS + colb);
#pragma unroll
        for (int j = 0; j < 8; ++j) acc[j] += (float)v0[j];
        i += 4;
    }
    if (i < hi && sub < hi - i) {
        bhalf8 v0 = *(const bhalf8*)(m + (size_t)eidx[i + sub] * IN_FEATS + colb);
#pragma unroll
        for (int j = 0; j < 8; ++j) acc[j] += (float)v0[j];
    }
#pragma unroll
    for (int j = 0; j < 8; ++j) {
        acc[j] += __shfl_xor(acc[j], 16);
        acc[j] += __shfl_xor(acc[j], 32);
    }
    if (sub == 0) {
        bhalf8 o;
#pragma unroll
        for (int j = 0; j < 8; ++j) o[j] = (bhalf)acc[j];
        *(bhalf8*)(agg + (size_t)n * IN_FEATS + colb) = o;
    }
}

// ---------------------------------------------------------------------------
// Gather-aggregate, layer 2 with fused BN1 (sum identity).
// ---------------------------------------------------------------------------
__global__ __launch_bounds__(256) void edge_gather2_bn(const bhalf* __restrict__ m,
                                                       const int* __restrict__ offsets,
                                                       const int* __restrict__ eidx,
                                                       const float* __restrict__ bnstats,
                                                       const float* __restrict__ bng,
                                                       const float* __restrict__ bnbe,
                                                       float inv_n,
                                                       bhalf* __restrict__ agg)
{
    int gidx = blockIdx.x * blockDim.x + threadIdx.x;
    int n = gidx >> 6, lane = gidx & 63;
    if (n >= N_NODES) return;
    int lo = offsets[n], hi = offsets[n + 1];
    int sub = lane >> 5;
    int colb = (lane & 31) * 8;
    float acc[8] = {};
    int i = lo;
    for (; i + 8 <= hi; i += 8) {
        bhalf8 v0 = *(const bhalf8*)(m + (size_t)eidx[i + sub] * HID + colb);
        bhalf8 v1 = *(const bhalf8*)(m + (size_t)eidx[i + 2 + sub] * HID + colb);
        bhalf8 v2 = *(const bhalf8*)(m + (size_t)eidx[i + 4 + sub] * HID + colb);
        bhalf8 v3 = *(const bhalf8*)(m + (size_t)eidx[i + 6 + sub] * HID + colb);
#pragma unroll
        for (int j = 0; j < 8; ++j)
            acc[j] += ((float)v0[j] + (float)v1[j]) + ((float)v2[j] + (float)v3[j]);
    }
    for (; i + 2 <= hi; i += 2) {
        bhalf8 v0 = *(const bhalf8*)(m + (size_t)eidx[i + sub] * HID + colb);
#pragma unroll
        for (int j = 0; j < 8; ++j) acc[j] += (float)v0[j];
    }
    if (i < hi && sub == 0) {
        bhalf8 v0 = *(const bhalf8*)(m + (size_t)eidx[i] * HID + colb);
#pragma unroll
        for (int j = 0; j < 8; ++j) acc[j] += (float)v0[j];
    }
#pragma unroll
    for (int j = 0; j < 8; ++j)
        acc[j] += __shfl_xor(acc[j], 32);
    if (sub == 0) {
        float d = (float)(hi - lo);
        bhalf8 o;
#pragma unroll
        for (int j = 0; j < 8; ++j) {
            int c = colb + j;
            float mu = bnstats[c] * inv_n;
            float rs = rsqrtf(bnstats[HID + c] * inv_n - mu * mu + 1e-5f);
            float s = bng[c] * rs;
            float tt = bnbe[c] - mu * s;
            o[j] = (bhalf)(acc[j] * s + d * tt);
        }
        *(bhalf8*)(agg + (size_t)n * HID + colb) = o;
    }
}

// ---------------------------------------------------------------------------
// Fused BN2 + attention weight + weighted-sum/max readout. Block per graph,
// thread = feature column. h stays fp32 (BN applied inline from raw stats).
// ---------------------------------------------------------------------------
__global__ __launch_bounds__(256) void readout_bn(const bhalf* __restrict__ v,
                                                  const float* __restrict__ stats,
                                                  float inv_n,
                                                  const float* __restrict__ g,
                                                  const float* __restrict__ be,
                                                  const float* __restrict__ awW,
                                                  const float* __restrict__ awb,
                                                  const int* __restrict__ gid,
                                                  bhalf* __restrict__ z)
{
    int gr = blockIdx.x, col = threadIdx.x;
    int lane = col & 63, wid = col >> 6;
    // BN params for my column
    float mu = stats[col] * inv_n;
    float rs = rsqrtf(stats[HID + col] * inv_n - mu * mu + 1e-5f);
    float s = g[col] * rs;
    float tt = be[col] - mu * s;
    float aw = awW[col];
    float ab = awb[0];
    // node range via binary search on sorted gid
    int lo = 0, hi = N_NODES;
    while (lo < hi) { int mid = (lo + hi) >> 1; if (gid[mid] < gr) lo = mid + 1; else hi = mid; }
    int start = lo;
    hi = N_NODES;
    while (lo < hi) { int mid = (lo + hi) >> 1; if (gid[mid] <= gr) lo = mid + 1; else hi = mid; }
    int end = lo;

    __shared__ float red[4];
    float sum = 0.f, mx = -INFINITY;
    for (int n = start; n < end; ++n) {
        float h = (float)v[(size_t)n * HID + col] * s + tt;
        float d = h * aw;
#pragma unroll
        for (int off = 32; off > 0; off >>= 1) d += __shfl_xor(d, off);
        if (lane == 0) red[wid] = d;
        __syncthreads();
        float w = 1.f / (1.f + expf(-(red[0] + red[1] + red[2] + red[3] + ab)));
        __syncthreads();
        sum = fmaf(h, w, sum);
        mx = fmaxf(mx, h);
    }
    z[(size_t)gr * 1024 + col] = (bhalf)sum;
    z[(size_t)gr * 1024 + HID + col] = (bhalf)mx;
}

// ---------------------------------------------------------------------------
extern "C" void kernel_launch(void* const* d_in, const int* in_sizes, int n_in,
                              void* d_out, int out_size, void* d_ws, size_t ws_size,
                              hipStream_t stream)
{
    (void)in_sizes; (void)n_in; (void)out_size; (void)ws_size;

    const float* node_feats = (const float*)d_in[0];
    const float* rdkit      = (const float*)d_in[1];
    const int*   src        = (const int*)d_in[2];
    const int*   dst        = (const int*)d_in[3];
    const int*   gid        = (const int*)d_in[4];
    const float* W1  = (const float*)d_in[5];
    const float* b1  = (const float*)d_in[6];
    const float* rW1 = (const float*)d_in[7];
    const float* rb1 = (const float*)d_in[8];
    const float* g1  = (const float*)d_in[9];
    const float* be1 = (const float*)d_in[10];
    const float* W2  = (const float*)d_in[11];
    const float* b2  = (const float*)d_in[12];
    const float* rW2 = (const float*)d_in[13];
    const float* rb2 = (const float*)d_in[14];
    const float* g2  = (const float*)d_in[15];
    const float* be2 = (const float*)d_in[16];
    const float* aw_W  = (const float*)d_in[17];
    const float* aw_b  = (const float*)d_in[18];
    const float* rk_W1 = (const float*)d_in[19];
    const float* rk_b1 = (const float*)d_in[20];
    const float* rk_W2 = (const float*)d_in[21];
    const float* rk_b2 = (const float*)d_in[22];
    const float* c_W1  = (const float*)d_in[23];
    const float* c_b1  = (const float*)d_in[24];
    const float* c_W2  = (const float*)d_in[25];
    const float* c_b2  = (const float*)d_in[26];
    const float* c_W3  = (const float*)d_in[27];
    const float* c_b3  = (const float*)d_in[28];

    float* out = (float*)d_out;

    const size_t NODE = (size_t)N_NODES * HID;         // 5,120,000
    bhalf* nfb   = (bhalf*)d_ws;                       // [20000,128]
    bhalf* aggb  = nfb + (size_t)N_NODES * IN_FEATS;   // [20000,256]
    bhalf* vb    = aggb + NODE;                        // [20000,256] layer-1 v
    bhalf* vb2   = vb + NODE;                          // [20000,256] layer-2 v
    bhalf* W1cat = vb2 + NODE;                         // [512,128]
    bhalf* W2cat = W1cat + 512 * 128;                  // [512,256]
    bhalf* rkW1t = W2cat + 512 * 256;                  // [1024,2048]
    bhalf* rkW2t = rkW1t + 2048 * 1024;                // [512,1024]
    bhalf* cW1t  = rkW2t + 1024 * 512;                 // [1024,1024]
    bhalf* cW2t  = cW1t + 1024 * 1024;                 // [512,1024]
    bhalf* rdkb  = cW2t + 1024 * 512;                  // [512,2048]
    // zero region: stats1|stats2|counts|cursor contiguous (41024 x 4B)
    float* stats1 = (float*)(rdkb + 512 * 2048);       // 512 raw sum|sumsq
    float* stats2 = stats1 + 512;                      // 512
    int*   counts = (int*)(stats2 + 512);              // N
    int*   cursor = counts + N_NODES;                  // N
    int*   offsets = cursor + N_NODES;                 // N+1
    int*   eidx    = offsets + N_NODES + 1;            // N_EDGES
    int*   bsum    = eidx + N_EDGES;                   // 128
    bhalf* zb    = (bhalf*)(bsum + 128);               // [512,1024]
    float* spart = (float*)(zb + 512 * 1024);          // 4x512x1024 fp32 (8MB)
    float* spart2 = spart + 4 * 512 * 1024;            // 8x512x512 fp32 (8MB)

    dim3 blk(256);
    const int EPB = (N_EDGES + 255) / 256;
    const int NPB = (N_NODES + 255) / 256;             // 79
    const int NWAVE = (N_NODES * 64) / 256;            // 5000: wave per node
    dim3 gfused(HID / 64, (N_NODES + 63) / 64);        // (4, 313)

    // ---------------- prep: weights + inputs + zeroing (1 launch) ----------
    PrepTab tab;
    tab.e[0] = {W1,    W1cat,             128, 256,   32};
    tab.e[1] = {rW1,   W1cat + 256 * 128, 128, 256,   64};
    tab.e[2] = {W2,    W2cat,             256, 256,  128};
    tab.e[3] = {rW2,   W2cat + 256 * 256, 256, 256,  192};
    tab.e[4] = {rk_W1, rkW1t,            2048, 1024, 2240};
    tab.e[5] = {rk_W2, rkW2t,            1024, 512,  2752};
    tab.e[6] = {c_W1,  cW1t,             1024, 1024, 3776};
    tab.e[7] = {c_W2,  cW2t,             1024, 512,  4288};
    tab.ca = node_feats; tab.coa = nfb;  tab.n4a = N_NODES * IN_FEATS / 4;
    tab.cb = rdkit;      tab.cob = rdkb; tab.n4b = 512 * 2048 / 4;
    tab.zbase = (uint4*)stats1;
    tab.zn = (1024 + 2 * N_NODES) / 4;                 // 41024 ints -> 10256 uint4
    const int ZB = (tab.zn + 255) / 256;               // 41
    prep_batch<<<WTILES + CONVB + ZB, blk, 0, stream>>>(tab);

    // ---------------- CSR build ----------------
    csr_count<<<EPB, blk, 0, stream>>>(dst, counts);
    csr_scan_a<<<NPB, blk, 0, stream>>>(counts, bsum);
    csr_scan_c<<<NPB, blk, 0, stream>>>(counts, bsum, NPB, offsets);
    csr_fill<<<EPB, blk, 0, stream>>>(src, dst, offsets, cursor, eidx);
    csr_sort_wave<<<NWAVE, blk, 0, stream>>>(offsets, eidx);

    // ---------------- Layer 1: gather -> fused GEMM(v,stats) ----------------
    edge_gather1<<<NWAVE, blk, 0, stream>>>(nfb, offsets, eidx, aggb);
    gcn_gemm_fused<0><<<gfused, blk, 0, stream>>>(aggb, nfb, W1cat, W1cat + 256 * 128,
                                                  b1, rb1, vb, stats1, N_NODES, IN_FEATS,
                                                  nullptr, nullptr, nullptr, 0.f);

    // ---------------- Layer 2: BN1 fused into gather + GEMM Ax path ---------
    edge_gather2_bn<<<NWAVE, blk, 0, stream>>>(vb, offsets, eidx,
                                               stats1, g1, be1, 1.0f / N_NODES, aggb);
    gcn_gemm_fused<1><<<gfused, blk, 0, stream>>>(aggb, vb, W2cat, W2cat + 256 * 256,
                                                  b2, rb2, vb2, stats2, N_NODES, HID,
                                                  stats1, g1, be1, 1.0f / N_NODES);

    // ---------------- Readout (BN2 + attention + sum/max fused) ----------
    readout_bn<<<N_GRAPHS, HID, 0, stream>>>(vb2, stats2, 1.0f / N_NODES, g2, be2,
                                             aw_W, aw_b, gid, zb);

    // ---------------- RDKit branch: rk1 -> [combine-in] rk2 -> zb ----------
    gemm_mfma<0,0,0><<<dim3(16, 8, 4), blk, 0, stream>>>(rdkb, rkW1t, spart, nullptr,
                                                         nullptr, 512, 2048, 1024);
    gemm_mfma<0,0,4><<<dim3(8, 8, 8), blk, 0, stream>>>(spart, rkW2t, spart2, nullptr,
                                                        rk_b1, 512, 1024, 512);
    splitk_combine<1,1><<<256, blk, 0, stream>>>(spart2, 8, 512, 512, 1024, rk_b2, zb + 512);

    // ---------------- Combined head: c1 -> [combine-in] c2 -> dot ----------
    gemm_mfma<0,0,0><<<dim3(16, 8, 4), blk, 0, stream>>>(zb, cW1t, spart, nullptr,
                                                         nullptr, 512, 1024, 1024);
    gemm_mfma<0,0,4><<<dim3(8, 8, 8), blk, 0, stream>>>(spart, cW2t, spart2, nullptr,
                                                        c_b1, 512, 1024, 512);
    splitk_combine_dot<<<512, 128, 0, stream>>>(spart2, 8, 512, 512, c_b2, c_W3, c_b3, out);
}

// Round 16
// 226.822 us; speedup vs baseline: 1.0519x; 1.0519x over previous
//
#include <hip/hip_runtime.h>
#include <hip/hip_bf16.h>
#include <cstdint>
#include <cstddef>

#define N_NODES 20000
#define N_EDGES 320000
#define N_GRAPHS 512
#define IN_FEATS 128
#define HID 256

typedef __bf16 bhalf;
typedef __bf16 bhalf8 __attribute__((ext_vector_type(8)));
typedef __bf16 bhalf4 __attribute__((ext_vector_type(4)));
typedef __bf16 bhalf2 __attribute__((ext_vector_type(2)));
typedef float f32x4 __attribute__((ext_vector_type(4)));

// Bijective XCD-aware block swizzle (m204).
__device__ __forceinline__ int2 xcd_swz(int bx, int by, int nbx, int nby)
{
    int lid = by * nbx + bx;
    int nwg = nbx * nby;
    int q = nwg >> 3, r = nwg & 7;
    int xcd = lid & 7, loc = lid >> 3;
    int s = (xcd < r ? xcd * (q + 1) : r * (q + 1) + (xcd - r) * q) + loc;
    return make_int2(s % nbx, s / nbx);
}

// ---------------------------------------------------------------------------
// bf16 MFMA GEMM (head layers): C = A @ Bt^T. 64x64 tile, BK=64, 4 waves.
// Split-K via gridDim.z (fp32 partials). XCD-swizzled.
// CIN>0: A operand is CIN fp32 split-K partial planes of the PREVIOUS GEMM;
// staging sums them + biasA + relu -> bf16 inline.
// ---------------------------------------------------------------------------
template<int RELU, int OUTBF16, int CIN>
__global__ __launch_bounds__(256) void gemm_mfma(const void* __restrict__ Av,
                                                 const bhalf* __restrict__ Bt,
                                                 void* __restrict__ Cv,
                                                 const float* __restrict__ bias,
                                                 const float* __restrict__ biasA,
                                                 int M, int K, int ldc)
{
    __shared__ bhalf As[64 * 64];
    __shared__ bhalf Bs[64 * 64];

    const int t = threadIdx.x;
    const int lane = t & 63, wid = t >> 6;
    const int wm0 = (wid >> 1) * 32, wn0 = (wid & 1) * 32;
    int2 bsw = xcd_swz(blockIdx.x, blockIdx.y, gridDim.x, gridDim.y);
    const int m0 = bsw.y * 64, n0 = bsw.x * 64;
    const int S = gridDim.z, kz = blockIdx.z;
    const int Ks = K / S;

    const int srow = t >> 2;
    const int sc0 = (t & 3) << 3;

    f32x4 acc[2][2] = {};
    uint4 ra0, ra1, rb0, rb1;

    const int grow = m0 + srow;
    const bool mok = grow < M;
    const bhalf* Abase = (const bhalf*)Av + (size_t)grow * K + (size_t)kz * Ks;
    const float* Afb   = (const float*)Av + (size_t)grow * K + (size_t)kz * Ks;
    const size_t zstr = (size_t)M * K;
    const bhalf* Bbase = Bt + (size_t)(n0 + srow) * K + (size_t)kz * Ks;

    if (CIN == 0) {
        ra0 = mok ? *(const uint4*)(Abase + sc0)      : make_uint4(0u,0u,0u,0u);
        ra1 = mok ? *(const uint4*)(Abase + sc0 + 32) : make_uint4(0u,0u,0u,0u);
    }
    rb0 = *(const uint4*)(Bbase + sc0);
    rb1 = *(const uint4*)(Bbase + sc0 + 32);

    const int swz = (srow & 7) << 3;
    for (int k0 = 0; k0 < Ks; k0 += 64) {
        __syncthreads();
        if (CIN == 0) {
            *(uint4*)&As[srow * 64 + (sc0 ^ swz)]        = ra0;
            *(uint4*)&As[srow * 64 + ((sc0 + 32) ^ swz)] = ra1;
        } else {
            int kg = kz * Ks + k0;
            float a0[8], a1[8];
#pragma unroll
            for (int j = 0; j < 8; ++j) {
                a0[j] = biasA[kg + sc0 + j];
                a1[j] = biasA[kg + sc0 + 32 + j];
            }
            if (mok) {
#pragma unroll
                for (int z = 0; z < CIN; ++z) {
                    const float* p = Afb + (size_t)z * zstr + k0;
                    float4 q0 = *(const float4*)(p + sc0);
                    float4 q1 = *(const float4*)(p + sc0 + 4);
                    float4 q2 = *(const float4*)(p + sc0 + 32);
                    float4 q3 = *(const float4*)(p + sc0 + 36);
                    a0[0] += q0.x; a0[1] += q0.y; a0[2] += q0.z; a0[3] += q0.w;
                    a0[4] += q1.x; a0[5] += q1.y; a0[6] += q1.z; a0[7] += q1.w;
                    a1[0] += q2.x; a1[1] += q2.y; a1[2] += q2.z; a1[3] += q2.w;
                    a1[4] += q3.x; a1[5] += q3.y; a1[6] += q3.z; a1[7] += q3.w;
                }
            }
            bhalf8 o0, o1;
#pragma unroll
            for (int j = 0; j < 8; ++j) {
                o0[j] = (bhalf)(mok ? fmaxf(a0[j], 0.f) : 0.f);
                o1[j] = (bhalf)(mok ? fmaxf(a1[j], 0.f) : 0.f);
            }
            *(bhalf8*)&As[srow * 64 + (sc0 ^ swz)]        = o0;
            *(bhalf8*)&As[srow * 64 + ((sc0 + 32) ^ swz)] = o1;
        }
        *(uint4*)&Bs[srow * 64 + (sc0 ^ swz)]        = rb0;
        *(uint4*)&Bs[srow * 64 + ((sc0 + 32) ^ swz)] = rb1;
        __syncthreads();
        if (k0 + 64 < Ks) {
            if (CIN == 0) {
                const bhalf* An = Abase + k0 + 64;
                ra0 = mok ? *(const uint4*)(An + sc0)      : make_uint4(0u,0u,0u,0u);
                ra1 = mok ? *(const uint4*)(An + sc0 + 32) : make_uint4(0u,0u,0u,0u);
            }
            const bhalf* Bn = Bbase + k0 + 64;
            rb0 = *(const uint4*)(Bn + sc0);
            rb1 = *(const uint4*)(Bn + sc0 + 32);
        }
#pragma unroll
        for (int kb = 0; kb < 2; ++kb) {
            const int kc = kb * 32 + (lane >> 4) * 8;
            bhalf8 af[2], bfr[2];
#pragma unroll
            for (int i = 0; i < 2; ++i) {
                int rA = wm0 + i * 16 + (lane & 15);
                af[i] = *(const bhalf8*)&As[rA * 64 + (kc ^ ((rA & 7) << 3))];
                int rB = wn0 + i * 16 + (lane & 15);
                bfr[i] = *(const bhalf8*)&Bs[rB * 64 + (kc ^ ((rB & 7) << 3))];
            }
#pragma unroll
            for (int mi = 0; mi < 2; ++mi)
#pragma unroll
                for (int ni = 0; ni < 2; ++ni)
                    acc[mi][ni] = __builtin_amdgcn_mfma_f32_16x16x32_bf16(
                        af[mi], bfr[ni], acc[mi][ni], 0, 0, 0);
        }
    }

#pragma unroll
    for (int mi = 0; mi < 2; ++mi)
#pragma unroll
        for (int ni = 0; ni < 2; ++ni) {
            int col = n0 + wn0 + ni * 16 + (lane & 15);
            f32x4 v = acc[mi][ni];
            if (S > 1) {
#pragma unroll
                for (int r = 0; r < 4; ++r) {
                    int row = m0 + wm0 + mi * 16 + (lane >> 4) * 4 + r;
                    if (row < M)
                        ((float*)Cv)[((size_t)kz * M + row) * ldc + col] = v[r];
                }
            } else {
                float bb = bias ? bias[col] : 0.f;
#pragma unroll
                for (int r = 0; r < 4; ++r) {
                    int row = m0 + wm0 + mi * 16 + (lane >> 4) * 4 + r;
                    if (row < M) {
                        float x = v[r] + bb;
                        if (RELU) x = fmaxf(x, 0.f);
                        if (OUTBF16) ((bhalf*)Cv)[(size_t)row * ldc + col] = (bhalf)x;
                        else         ((float*)Cv)[(size_t)row * ldc + col] = x;
                    }
                }
            }
        }
}

// ---------------------------------------------------------------------------
// Fused GCN layer GEMM, two-phase (m then r). BN=1: BN1 affine applied to the
// Ax tile during LDS staging. vout must NOT alias Aagg/Ax (round-13 lesson).
// ---------------------------------------------------------------------------
template<int BN>
__global__ __launch_bounds__(256) void gcn_gemm_fused(const bhalf* __restrict__ Aagg,
                                                      const bhalf* __restrict__ Ax,
                                                      const bhalf* __restrict__ BW,
                                                      const bhalf* __restrict__ BrW,
                                                      const float* __restrict__ b,
                                                      const float* __restrict__ rb,
                                                      bhalf* __restrict__ vout,
                                                      float* __restrict__ stats,
                                                      int M, int K,
                                                      const float* __restrict__ bnstats,
                                                      const float* __restrict__ bng,
                                                      const float* __restrict__ bnbe,
                                                      float inv_n)
{
    __shared__ bhalf As[64 * 64];
    __shared__ bhalf Bs[64 * 64];
    __shared__ float ssum[64], ssq[64];
    __shared__ float bnS[256], bnB[256];

    const int t = threadIdx.x;
    const int lane = t & 63, wid = t >> 6;
    const int wm0 = (wid >> 1) * 32, wn0 = (wid & 1) * 32;
    int2 bsw = xcd_swz(blockIdx.x, blockIdx.y, gridDim.x, gridDim.y);
    const int m0 = bsw.y * 64, n0 = bsw.x * 64;

    const int srow = t >> 2;
    const int sc0 = (t & 3) << 3;
    const int nk = K >> 6;

    if (BN && t < K) {
        float mu = bnstats[t] * inv_n;
        float rs = rsqrtf(bnstats[K + t] * inv_n - mu * mu + 1e-5f);
        float s = bng[t] * rs;
        bnS[t] = s;
        bnB[t] = bnbe[t] - mu * s;
    }

    f32x4 accM[2][2] = {};
    f32x4 accR[2][2] = {};
    uint4 ra0, ra1, rb0, rb1;

    const bool mok = (m0 + srow) < M;
    const bhalf* A0r = Aagg + (size_t)(m0 + srow) * K;
    const bhalf* A1r = Ax + (size_t)(m0 + srow) * K;
    const bhalf* B0r = BW + (size_t)(n0 + srow) * K;
    const bhalf* B1r = BrW + (size_t)(n0 + srow) * K;

    ra0 = mok ? *(const uint4*)(A0r + sc0)      : make_uint4(0u,0u,0u,0u);
    ra1 = mok ? *(const uint4*)(A0r + sc0 + 32) : make_uint4(0u,0u,0u,0u);
    rb0 = *(const uint4*)(B0r + sc0);
    rb1 = *(const uint4*)(B0r + sc0 + 32);

    const int swz = (srow & 7) << 3;
    const int total = 2 * nk;
    if (BN) __syncthreads();
    for (int ii = 0; ii < total; ++ii) {
        __syncthreads();
        if (BN && ii >= nk) {
            int kb0 = ((ii - nk) << 6) + sc0;
            bhalf8 a0 = *(bhalf8*)&ra0, a1 = *(bhalf8*)&ra1;
#pragma unroll
            for (int j = 0; j < 8; ++j) {
                a0[j] = (bhalf)((float)a0[j] * bnS[kb0 + j] + bnB[kb0 + j]);
                a1[j] = (bhalf)((float)a1[j] * bnS[kb0 + 32 + j] + bnB[kb0 + 32 + j]);
            }
            ra0 = *(uint4*)&a0; ra1 = *(uint4*)&a1;
        }
        *(uint4*)&As[srow * 64 + (sc0 ^ swz)]        = ra0;
        *(uint4*)&As[srow * 64 + ((sc0 + 32) ^ swz)] = ra1;
        *(uint4*)&Bs[srow * 64 + (sc0 ^ swz)]        = rb0;
        *(uint4*)&Bs[srow * 64 + ((sc0 + 32) ^ swz)] = rb1;
        __syncthreads();
        int jj = ii + 1;
        if (jj < total) {
            bool seln = jj >= nk;
            int kk = (seln ? jj - nk : jj) << 6;
            const bhalf* Ab = (seln ? A1r : A0r) + kk;
            const bhalf* Bb = (seln ? B1r : B0r) + kk;
            ra0 = mok ? *(const uint4*)(Ab + sc0)      : make_uint4(0u,0u,0u,0u);
            ra1 = mok ? *(const uint4*)(Ab + sc0 + 32) : make_uint4(0u,0u,0u,0u);
            rb0 = *(const uint4*)(Bb + sc0);
            rb1 = *(const uint4*)(Bb + sc0 + 32);
        }
        const bool selc = ii >= nk;
#pragma unroll
        for (int kb = 0; kb < 2; ++kb) {
            const int kc = kb * 32 + (lane >> 4) * 8;
            bhalf8 af[2], bfr[2];
#pragma unroll
            for (int i = 0; i < 2; ++i) {
                int rA = wm0 + i * 16 + (lane & 15);
                af[i] = *(const bhalf8*)&As[rA * 64 + (kc ^ ((rA & 7) << 3))];
                int rB = wn0 + i * 16 + (lane & 15);
                bfr[i] = *(const bhalf8*)&Bs[rB * 64 + (kc ^ ((rB & 7) << 3))];
            }
            if (!selc) {
#pragma unroll
                for (int mi = 0; mi < 2; ++mi)
#pragma unroll
                    for (int ni = 0; ni < 2; ++ni)
                        accM[mi][ni] = __builtin_amdgcn_mfma_f32_16x16x32_bf16(
                            af[mi], bfr[ni], accM[mi][ni], 0, 0, 0);
            } else {
#pragma unroll
                for (int mi = 0; mi < 2; ++mi)
#pragma unroll
                    for (int ni = 0; ni < 2; ++ni)
                        accR[mi][ni] = __builtin_amdgcn_mfma_f32_16x16x32_bf16(
                            af[mi], bfr[ni], accR[mi][ni], 0, 0, 0);
            }
        }
    }

    if (t < 64) { ssum[t] = 0.f; ssq[t] = 0.f; }
    __syncthreads();
    float sloc[2] = {0.f, 0.f}, s2loc[2] = {0.f, 0.f};
#pragma unroll
    for (int ni = 0; ni < 2; ++ni) {
        int cl = wn0 + ni * 16 + (lane & 15);
        int c = n0 + cl;
        float bb = b[c], rbb = rb[c];
#pragma unroll
        for (int mi = 0; mi < 2; ++mi) {
            f32x4 a0v = accM[mi][ni], a1v = accR[mi][ni];
#pragma unroll
            for (int r = 0; r < 4; ++r) {
                int row = m0 + wm0 + mi * 16 + (lane >> 4) * 4 + r;
                if (row < M) {
                    float x = fmaxf(a0v[r] + bb, 0.f) + fmaxf(a1v[r] + rbb, 0.f);
                    vout[(size_t)row * HID + c] = (bhalf)x;
                    sloc[ni] += x;
                    s2loc[ni] += x * x;
                }
            }
        }
        atomicAdd(&ssum[cl], sloc[ni]);
        atomicAdd(&ssq[cl], s2loc[ni]);
    }
    __syncthreads();
    if (t < 64) {
        atomicAdd(&stats[n0 + t], ssum[t]);
        atomicAdd(&stats[HID + n0 + t], ssq[t]);
    }
}

// sum S split-K partials + bias + act (used once: rk2 -> zb)
template<int RELU, int OUTBF16>
__global__ __launch_bounds__(256) void splitk_combine(const float* __restrict__ part,
                                                      int S, int M, int N, int ldo,
                                                      const float* __restrict__ bias,
                                                      void* __restrict__ outv)
{
    int i = blockIdx.x * blockDim.x + threadIdx.x;
    int n4 = N >> 2;
    if (i >= M * n4) return;
    int row = i / n4, c4 = (i - row * n4) << 2;
    float4 s = make_float4(0.f, 0.f, 0.f, 0.f);
    for (int z = 0; z < S; ++z) {
        float4 p = *(const float4*)(part + ((size_t)z * M + row) * N + c4);
        s.x += p.x; s.y += p.y; s.z += p.z; s.w += p.w;
    }
    float4 bb = *(const float4*)(bias + c4);
    s.x += bb.x; s.y += bb.y; s.z += bb.z; s.w += bb.w;
    if (RELU) {
        s.x = fmaxf(s.x, 0.f); s.y = fmaxf(s.y, 0.f);
        s.z = fmaxf(s.z, 0.f); s.w = fmaxf(s.w, 0.f);
    }
    if (OUTBF16) {
        bhalf4 o = {(bhalf)s.x, (bhalf)s.y, (bhalf)s.z, (bhalf)s.w};
        *(bhalf4*)((bhalf*)outv + (size_t)row * ldo + c4) = o;
    } else {
        *(float4*)((float*)outv + (size_t)row * ldo + c4) = s;
    }
}

// last head layer: combine S partials + bias + relu, dot with W3
__global__ __launch_bounds__(128) void splitk_combine_dot(const float* __restrict__ part,
                                                          int S, int M, int N,
                                                          const float* __restrict__ bias,
                                                          const float* __restrict__ W3,
                                                          const float* __restrict__ b3,
                                                          float* __restrict__ out)
{
    int row = blockIdx.x, t = threadIdx.x;
    int c4 = t << 2;
    float4 s = make_float4(0.f, 0.f, 0.f, 0.f);
    for (int z = 0; z < S; ++z) {
        float4 p = *(const float4*)(part + ((size_t)z * M + row) * N + c4);
        s.x += p.x; s.y += p.y; s.z += p.z; s.w += p.w;
    }
    float4 bb = *(const float4*)(bias + c4);
    float4 w = *(const float4*)(W3 + c4);
    float d = fmaxf(s.x + bb.x, 0.f) * w.x + fmaxf(s.y + bb.y, 0.f) * w.y
            + fmaxf(s.z + bb.z, 0.f) * w.z + fmaxf(s.w + bb.w, 0.f) * w.w;
#pragma unroll
    for (int off = 32; off > 0; off >>= 1) d += __shfl_xor(d, off);
    __shared__ float ws2[2];
    if ((t & 63) == 0) ws2[t >> 6] = d;
    __syncthreads();
    if (t == 0) out[row] = ws2[0] + ws2[1] + b3[0];
}

// ---------------------------------------------------------------------------
// Prep mega-kernel: weight transpose+convert | input conversion | zeroing.
// ---------------------------------------------------------------------------
struct WEnt { const float* src; bhalf* dst; int K; int N; int tiles_end; };
struct PrepTab {
    WEnt e[8];
    const float* ca; bhalf* coa; int n4a;
    const float* cb; bhalf* cob; int n4b;
    uint4* zbase; int zn;
};

#define WTILES 4288
#define CONVB  3524

__global__ __launch_bounds__(256) void prep_batch(PrepTab tab)
{
    __shared__ float tile[32][33];
    int tb = blockIdx.x;
    int t = threadIdx.x;
    if (tb < WTILES) {
        int idx = 0;
#pragma unroll
        for (int i = 0; i < 8; ++i)
            if (tb >= tab.e[i].tiles_end) idx = i + 1;
        const WEnt& E = tab.e[idx];
        int t0 = idx ? tab.e[idx - 1].tiles_end : 0;
        int lt = tb - t0;
        int tX = E.N >> 5;
        int bx = (lt % tX) << 5;
        int by = (lt / tX) << 5;
        int tx = t & 31, ty = t >> 5;
#pragma unroll
        for (int i = 0; i < 32; i += 8)
            tile[ty + i][tx] = E.src[(size_t)(by + ty + i) * E.N + bx + tx];
        __syncthreads();
#pragma unroll
        for (int i = 0; i < 32; i += 8)
            E.dst[(size_t)(bx + ty + i) * E.K + by + tx] = (bhalf)tile[tx][ty + i];
    } else if (tb < WTILES + CONVB) {
        int i = (tb - WTILES) * 256 + t;
        const float* s; bhalf* d; int j;
        if (i < tab.n4a) { s = tab.ca; d = tab.coa; j = i; }
        else { j = i - tab.n4a; if (j >= tab.n4b) return; s = tab.cb; d = tab.cob; }
        float4 v = ((const float4*)s)[j];
        bhalf4 o = {(bhalf)v.x, (bhalf)v.y, (bhalf)v.z, (bhalf)v.w};
        ((bhalf4*)d)[j] = o;
    } else {
        int j = (tb - WTILES - CONVB) * 256 + t;
        if (j < tab.zn) tab.zbase[j] = make_uint4(0u, 0u, 0u, 0u);
    }
}

// ---------------------------------------------------------------------------
// CSR build
// ---------------------------------------------------------------------------
__global__ void csr_count(const int* __restrict__ dst, int* __restrict__ counts)
{
    int e = blockIdx.x * blockDim.x + threadIdx.x;
    if (e >= N_EDGES) return;
    atomicAdd(&counts[dst[e]], 1);
}

__global__ __launch_bounds__(256) void csr_scan_a(const int* __restrict__ counts,
                                                  int* __restrict__ bsum)
{
    int i = blockIdx.x * 256 + threadIdx.x;
    int v = (i < N_NODES) ? counts[i] : 0;
#pragma unroll
    for (int off = 32; off > 0; off >>= 1) v += __shfl_down(v, off);
    __shared__ int ws[4];
    if ((threadIdx.x & 63) == 0) ws[threadIdx.x >> 6] = v;
    __syncthreads();
    if (threadIdx.x == 0) bsum[blockIdx.x] = ws[0] + ws[1] + ws[2] + ws[3];
}

__global__ __launch_bounds__(256) void csr_scan_c(const int* __restrict__ counts,
                                                  const int* __restrict__ bsum, int nb,
                                                  int* __restrict__ offsets)
{
    int t = threadIdx.x, b = blockIdx.x;
    int i = b * 256 + t;
    int v = (i < N_NODES) ? counts[i] : 0;
    int x = v;
#pragma unroll
    for (int off = 1; off < 64; off <<= 1) {
        int y = __shfl_up(x, off);
        if ((t & 63) >= off) x += y;
    }
    __shared__ int wsum[4];
    __shared__ int tmp[128];
    __shared__ int addsh;
    if ((t & 63) == 63) wsum[t >> 6] = x;
    if (t < 128) tmp[t] = (t < nb) ? bsum[t] : 0;
    __syncthreads();
    if (t == 0) {
        int a = 0;
        for (int j = 0; j < b; ++j) a += tmp[j];
        addsh = a;
    }
    __syncthreads();
    int add = addsh;
    for (int w = 0; w < (t >> 6); ++w) add += wsum[w];
    int excl = x - v + add;
    if (i < N_NODES) offsets[i] = excl;
    if (i == N_NODES - 1) offsets[N_NODES] = excl + v;
}

__global__ void csr_fill(const int* __restrict__ src, const int* __restrict__ dst,
                         const int* __restrict__ offsets, int* __restrict__ cursor,
                         int* __restrict__ eidx)
{
    int e = blockIdx.x * blockDim.x + threadIdx.x;
    if (e >= N_EDGES) return;
    int d = dst[e];
    int slot = offsets[d] + atomicAdd(&cursor[d], 1);
    eidx[slot] = src[e];
}

__global__ void csr_sort_wave(const int* __restrict__ offsets, int* __restrict__ eidx)
{
    int gidx = blockIdx.x * blockDim.x + threadIdx.x;
    int n = gidx >> 6, lane = gidx & 63;
    if (n >= N_NODES) return;
    int lo = offsets[n], hi = offsets[n + 1];
    int cnt = hi - lo;
    if (cnt <= 1) return;
    if (cnt <= 64) {
        int v = (lane < cnt) ? eidx[lo + lane] : 0x7fffffff;
        int rank = 0;
        for (int j = 0; j < cnt; ++j) {
            int vj = __shfl(v, j);
            if (vj < v || (vj == v && j < lane)) ++rank;
        }
        if (lane < cnt) eidx[lo + rank] = v;
    } else if (lane == 0) {
        for (int i = lo + 1; i < hi; ++i) {
            int v = eidx[i]; int j = i - 1;
            while (j >= lo && eidx[j] > v) { eidx[j + 1] = eidx[j]; --j; }
            eidx[j + 1] = v;
        }
    }
}

// ---------------------------------------------------------------------------
// Gather-aggregate, layer 1 (128 cols): one wave = 4 edges/step, 16 lanes x
// 16B per row, shfl-xor combine across lane-groups.
// ---------------------------------------------------------------------------
__global__ __launch_bounds__(256) void edge_gather1(const bhalf* __restrict__ m,
                                                    const int* __restrict__ offsets,
                                                    const int* __restrict__ eidx,
                                                    bhalf* __restrict__ agg)
{
    int gidx = blockIdx.x * blockDim.x + threadIdx.x;
    int n = gidx >> 6, lane = gidx & 63;
    if (n >= N_NODES) return;
    int lo = offsets[n], hi = offsets[n + 1];
    int sub = lane >> 4;
    int colb = (lane & 15) * 8;
    float acc[8] = {};
    int i = lo;
    for (; i + 8 <= hi; i += 8) {
        bhalf8 v0 = *(const bhalf8*)(m + (size_t)eidx[i + sub] * IN_FEATS + colb);
        bhalf8 v1 = *(const bhalf8*)(m + (size_t)eidx[i + 4 + sub] * IN_FEATS + colb);
#pragma unroll
        for (int j = 0; j < 8; ++j) acc[j] += (float)v0[j] + (float)v1[j];
    }
    if (i + 4 <= hi) {
        bhalf8 v0 = *(const bhalf8*)(m + (size_t)eidx[i + sub] * IN_FEATS + colb);
#pragma unroll
        for (int j = 0; j < 8; ++j) acc[j] += (float)v0[j];
        i += 4;
    }
    if (i < hi && sub < hi - i) {
        bhalf8 v0 = *(const bhalf8*)(m + (size_t)eidx[i + sub] * IN_FEATS + colb);
#pragma unroll
        for (int j = 0; j < 8; ++j) acc[j] += (float)v0[j];
    }
#pragma unroll
    for (int j = 0; j < 8; ++j) {
        acc[j] += __shfl_xor(acc[j], 16);
        acc[j] += __shfl_xor(acc[j], 32);
    }
    if (sub == 0) {
        bhalf8 o;
#pragma unroll
        for (int j = 0; j < 8; ++j) o[j] = (bhalf)acc[j];
        *(bhalf8*)(agg + (size_t)n * IN_FEATS + colb) = o;
    }
}

// ---------------------------------------------------------------------------
// Gather-aggregate, layer 2 with fused BN1 (sum identity).
// ---------------------------------------------------------------------------
__global__ __launch_bounds__(256) void edge_gather2_bn(const bhalf* __restrict__ m,
                                                       const int* __restrict__ offsets,
                                                       const int* __restrict__ eidx,
                                                       const float* __restrict__ bnstats,
                                                       const float* __restrict__ bng,
                                                       const float* __restrict__ bnbe,
                                                       float inv_n,
                                                       bhalf* __restrict__ agg)
{
    int gidx = blockIdx.x * blockDim.x + threadIdx.x;
    int n = gidx >> 6, lane = gidx & 63;
    if (n >= N_NODES) return;
    int lo = offsets[n], hi = offsets[n + 1];
    int sub = lane >> 5;
    int colb = (lane & 31) * 8;
    float acc[8] = {};
    int i = lo;
    for (; i + 8 <= hi; i += 8) {
        bhalf8 v0 = *(const bhalf8*)(m + (size_t)eidx[i + sub] * HID + colb);
        bhalf8 v1 = *(const bhalf8*)(m + (size_t)eidx[i + 2 + sub] * HID + colb);
        bhalf8 v2 = *(const bhalf8*)(m + (size_t)eidx[i + 4 + sub] * HID + colb);
        bhalf8 v3 = *(const bhalf8*)(m + (size_t)eidx[i + 6 + sub] * HID + colb);
#pragma unroll
        for (int j = 0; j < 8; ++j)
            acc[j] += ((float)v0[j] + (float)v1[j]) + ((float)v2[j] + (float)v3[j]);
    }
    for (; i + 2 <= hi; i += 2) {
        bhalf8 v0 = *(const bhalf8*)(m + (size_t)eidx[i + sub] * HID + colb);
#pragma unroll
        for (int j = 0; j < 8; ++j) acc[j] += (float)v0[j];
    }
    if (i < hi && sub == 0) {
        bhalf8 v0 = *(const bhalf8*)(m + (size_t)eidx[i] * HID + colb);
#pragma unroll
        for (int j = 0; j < 8; ++j) acc[j] += (float)v0[j];
    }
#pragma unroll
    for (int j = 0; j < 8; ++j)
        acc[j] += __shfl_xor(acc[j], 32);
    if (sub == 0) {
        float d = (float)(hi - lo);
        bhalf8 o;
#pragma unroll
        for (int j = 0; j < 8; ++j) {
            int c = colb + j;
            float mu = bnstats[c] * inv_n;
            float rs = rsqrtf(bnstats[HID + c] * inv_n - mu * mu + 1e-5f);
            float s = bng[c] * rs;
            float tt = bnbe[c] - mu * s;
            o[j] = (bhalf)(acc[j] * s + d * tt);
        }
        *(bhalf8*)(agg + (size_t)n * HID + colb) = o;
    }
}

// ---------------------------------------------------------------------------
// Wave-per-node BN with inline finalize; writes bf16 h + node attention
// weight (round-14 structure — no barriers in any per-node loop).
// ---------------------------------------------------------------------------
__global__ __launch_bounds__(256) void bn_row_aw(const bhalf* __restrict__ v,
                                                 const float* __restrict__ stats,
                                                 float inv_n,
                                                 const float* __restrict__ g,
                                                 const float* __restrict__ be,
                                                 bhalf* __restrict__ outb,
                                                 const float* __restrict__ awW,
                                                 const float* __restrict__ awb,
                                                 float* __restrict__ w)
{
    int gidx = blockIdx.x * blockDim.x + threadIdx.x;
    int n = gidx >> 6, lane = gidx & 63;
    if (n >= N_NODES) return;
    int col = lane * 4;
    bhalf4 vv = *(const bhalf4*)(v + (size_t)n * HID + col);
    float4 sm = *(const float4*)(stats + col);
    float4 sq = *(const float4*)(stats + HID + col);
    float4 gg = *(const float4*)(g + col);
    float4 bb = *(const float4*)(be + col);
    float mux = sm.x * inv_n, muy = sm.y * inv_n, muz = sm.z * inv_n, muw = sm.w * inv_n;
    float rsx = rsqrtf(sq.x * inv_n - mux * mux + 1e-5f);
    float rsy = rsqrtf(sq.y * inv_n - muy * muy + 1e-5f);
    float rsz = rsqrtf(sq.z * inv_n - muz * muz + 1e-5f);
    float rsw = rsqrtf(sq.w * inv_n - muw * muw + 1e-5f);
    float4 o;
    o.x = gg.x * ((float)vv.x - mux) * rsx + bb.x;
    o.y = gg.y * ((float)vv.y - muy) * rsy + bb.y;
    o.z = gg.z * ((float)vv.z - muz) * rsz + bb.z;
    o.w = gg.w * ((float)vv.w - muw) * rsw + bb.w;
    bhalf4 ob = {(bhalf)o.x, (bhalf)o.y, (bhalf)o.z, (bhalf)o.w};
    *(bhalf4*)(outb + (size_t)n * HID + col) = ob;
    float4 wv = *(const float4*)(awW + col);
    float d = o.x * wv.x + o.y * wv.y + o.z * wv.z + o.w * wv.w;
#pragma unroll
    for (int off = 32; off > 0; off >>= 1) d += __shfl_xor(d, off);
    if (lane == 0) w[n] = 1.f / (1.f + expf(-(d + awb[0])));
}

// ---------------------------------------------------------------------------
__global__ __launch_bounds__(256) void readout(const bhalf* __restrict__ h,
                                               const float* __restrict__ w,
                                               const int* __restrict__ gid,
                                               bhalf* __restrict__ z)
{
    int g = blockIdx.x, col = threadIdx.x;
    int lo = 0, hi = N_NODES;
    while (lo < hi) { int mid = (lo + hi) >> 1; if (gid[mid] < g) lo = mid + 1; else hi = mid; }
    int start = lo;
    hi = N_NODES;
    while (lo < hi) { int mid = (lo + hi) >> 1; if (gid[mid] <= g) lo = mid + 1; else hi = mid; }
    int end = lo;
    float s = 0.f, mx = -INFINITY;
    for (int n = start; n < end; ++n) {
        float v = (float)h[(size_t)n * HID + col];
        s = fmaf(v, w[n], s);
        mx = fmaxf(mx, v);
    }
    z[(size_t)g * 1024 + col] = (bhalf)s;
    z[(size_t)g * 1024 + HID + col] = (bhalf)mx;
}

// ---------------------------------------------------------------------------
extern "C" void kernel_launch(void* const* d_in, const int* in_sizes, int n_in,
                              void* d_out, int out_size, void* d_ws, size_t ws_size,
                              hipStream_t stream)
{
    (void)in_sizes; (void)n_in; (void)out_size; (void)ws_size;

    const float* node_feats = (const float*)d_in[0];
    const float* rdkit      = (const float*)d_in[1];
    const int*   src        = (const int*)d_in[2];
    const int*   dst        = (const int*)d_in[3];
    const int*   gid        = (const int*)d_in[4];
    const float* W1  = (const float*)d_in[5];
    const float* b1  = (const float*)d_in[6];
    const float* rW1 = (const float*)d_in[7];
    const float* rb1 = (const float*)d_in[8];
    const float* g1  = (const float*)d_in[9];
    const float* be1 = (const float*)d_in[10];
    const float* W2  = (const float*)d_in[11];
    const float* b2  = (const float*)d_in[12];
    const float* rW2 = (const float*)d_in[13];
    const float* rb2 = (const float*)d_in[14];
    const float* g2  = (const float*)d_in[15];
    const float* be2 = (const float*)d_in[16];
    const float* aw_W  = (const float*)d_in[17];
    const float* aw_b  = (const float*)d_in[18];
    const float* rk_W1 = (const float*)d_in[19];
    const float* rk_b1 = (const float*)d_in[20];
    const float* rk_W2 = (const float*)d_in[21];
    const float* rk_b2 = (const float*)d_in[22];
    const float* c_W1  = (const float*)d_in[23];
    const float* c_b1  = (const float*)d_in[24];
    const float* c_W2  = (const float*)d_in[25];
    const float* c_b2  = (const float*)d_in[26];
    const float* c_W3  = (const float*)d_in[27];
    const float* c_b3  = (const float*)d_in[28];

    float* out = (float*)d_out;

    const size_t NODE = (size_t)N_NODES * HID;         // 5,120,000
    bhalf* nfb   = (bhalf*)d_ws;                       // [20000,128]
    bhalf* aggb  = nfb + (size_t)N_NODES * IN_FEATS;   // [20000,256]
    bhalf* vb    = aggb + NODE;                        // [20000,256] layer-1 v
    bhalf* vb2   = vb + NODE;                          // [20000,256] layer-2 v
    bhalf* h2b   = vb2 + NODE;                         // [20000,256] layer-2 h
    bhalf* W1cat = h2b + NODE;                         // [512,128]
    bhalf* W2cat = W1cat + 512 * 128;                  // [512,256]
    bhalf* rkW1t = W2cat + 512 * 256;                  // [1024,2048]
    bhalf* rkW2t = rkW1t + 2048 * 1024;                // [512,1024]
    bhalf* cW1t  = rkW2t + 1024 * 512;                 // [1024,1024]
    bhalf* cW2t  = cW1t + 1024 * 1024;                 // [512,1024]
    bhalf* rdkb  = cW2t + 1024 * 512;                  // [512,2048]
    // zero region: stats1|stats2|counts|cursor contiguous (41024 x 4B)
    float* stats1 = (float*)(rdkb + 512 * 2048);       // 512 raw sum|sumsq
    float* stats2 = stats1 + 512;                      // 512
    int*   counts = (int*)(stats2 + 512);              // N
    int*   cursor = counts + N_NODES;                  // N
    float* wbuf   = (float*)(cursor + N_NODES);        // 20000
    int*   offsets = (int*)(wbuf + N_NODES);           // N+1
    int*   eidx    = offsets + N_NODES + 1;            // N_EDGES
    int*   bsum    = eidx + N_EDGES;                   // 128
    bhalf* zb    = (bhalf*)(bsum + 128);               // [512,1024]
    float* spart = (float*)(zb + 512 * 1024);          // 4x512x1024 fp32 (8MB)
    float* spart2 = spart + 4 * 512 * 1024;            // 8x512x512 fp32 (8MB)

    dim3 blk(256);
    const int EPB = (N_EDGES + 255) / 256;
    const int NPB = (N_NODES + 255) / 256;             // 79
    const int NWAVE = (N_NODES * 64) / 256;            // 5000: wave per node
    dim3 gfused(HID / 64, (N_NODES + 63) / 64);        // (4, 313)

    // ---------------- prep: weights + inputs + zeroing (1 launch) ----------
    PrepTab tab;
    tab.e[0] = {W1,    W1cat,             128, 256,   32};
    tab.e[1] = {rW1,   W1cat + 256 * 128, 128, 256,   64};
    tab.e[2] = {W2,    W2cat,             256, 256,  128};
    tab.e[3] = {rW2,   W2cat + 256 * 256, 256, 256,  192};
    tab.e[4] = {rk_W1, rkW1t,            2048, 1024, 2240};
    tab.e[5] = {rk_W2, rkW2t,            1024, 512,  2752};
    tab.e[6] = {c_W1,  cW1t,             1024, 1024, 3776};
    tab.e[7] = {c_W2,  cW2t,             1024, 512,  4288};
    tab.ca = node_feats; tab.coa = nfb;  tab.n4a = N_NODES * IN_FEATS / 4;
    tab.cb = rdkit;      tab.cob = rdkb; tab.n4b = 512 * 2048 / 4;
    tab.zbase = (uint4*)stats1;
    tab.zn = (1024 + 2 * N_NODES) / 4;                 // 41024 ints -> 10256 uint4
    const int ZB = (tab.zn + 255) / 256;               // 41
    prep_batch<<<WTILES + CONVB + ZB, blk, 0, stream>>>(tab);

    // ---------------- CSR build ----------------
    csr_count<<<EPB, blk, 0, stream>>>(dst, counts);
    csr_scan_a<<<NPB, blk, 0, stream>>>(counts, bsum);
    csr_scan_c<<<NPB, blk, 0, stream>>>(counts, bsum, NPB, offsets);
    csr_fill<<<EPB, blk, 0, stream>>>(src, dst, offsets, cursor, eidx);
    csr_sort_wave<<<NWAVE, blk, 0, stream>>>(offsets, eidx);

    // ---------------- Layer 1: gather -> fused GEMM(v,stats) ----------------
    edge_gather1<<<NWAVE, blk, 0, stream>>>(nfb, offsets, eidx, aggb);
    gcn_gemm_fused<0><<<gfused, blk, 0, stream>>>(aggb, nfb, W1cat, W1cat + 256 * 128,
                                                  b1, rb1, vb, stats1, N_NODES, IN_FEATS,
                                                  nullptr, nullptr, nullptr, 0.f);

    // ---------------- Layer 2: BN1 fused into gather + GEMM Ax path ---------
    edge_gather2_bn<<<NWAVE, blk, 0, stream>>>(vb, offsets, eidx,
                                               stats1, g1, be1, 1.0f / N_NODES, aggb);
    gcn_gemm_fused<1><<<gfused, blk, 0, stream>>>(aggb, vb, W2cat, W2cat + 256 * 256,
                                                  b2, rb2, vb2, stats2, N_NODES, HID,
                                                  stats1, g1, be1, 1.0f / N_NODES);
    bn_row_aw<<<NWAVE, blk, 0, stream>>>(vb2, stats2, 1.0f / N_NODES, g2, be2,
                                         h2b, aw_W, aw_b, wbuf);

    // ---------------- Readout ----------------
    readout<<<N_GRAPHS, HID, 0, stream>>>(h2b, wbuf, gid, zb);

    // ---------------- RDKit branch: rk1 -> [combine-in] rk2 -> zb ----------
    gemm_mfma<0,0,0><<<dim3(16, 8, 4), blk, 0, stream>>>(rdkb, rkW1t, spart, nullptr,
                                                         nullptr, 512, 2048, 1024);
    gemm_mfma<0,0,4><<<dim3(8, 8, 8), blk, 0, stream>>>(spart, rkW2t, spart2, nullptr,
                                                        rk_b1, 512, 1024, 512);
    splitk_combine<1,1><<<256, blk, 0, stream>>>(spart2, 8, 512, 512, 1024, rk_b2, zb + 512);

    // ---------------- Combined head: c1 -> [combine-in] c2 -> dot ----------
    gemm_mfma<0,0,0><<<dim3(16, 8, 4), blk, 0, stream>>>(zb, cW1t, spart, nullptr,
                                                         nullptr, 512, 1024, 1024);
    gemm_mfma<0,0,4><<<dim3(8, 8, 8), blk, 0, stream>>>(spart, cW2t, spart2, nullptr,
                                                        c_b1, 512, 1024, 512);
    splitk_combine_dot<<<512, 128, 0, stream>>>(spart2, 8, 512, 512, c_b2, c_W3, c_b3, out);
}